// Round 6
// baseline (220.739 us; speedup 1.0000x reference)
//
#include <hip/hip_runtime.h>
#include <math.h>
#include <stdint.h>

#define Bn   2
#define Nn   1024
#define DIMn 512
#define NHn  8
#define HDn  64
#define QKVS 1536
#define EPSF 1e-7f

typedef __attribute__((ext_vector_type(8))) short short8;
typedef __attribute__((ext_vector_type(4))) float floatx4;

// ---------------- bf16 helpers (RNE) ----------------
__device__ __forceinline__ unsigned short f2bf(float f) {
  union { float f; uint32_t u; } v; v.f = f;
  uint32_t u = v.u;
  return (unsigned short)((u + 0x7FFFu + ((u >> 16) & 1u)) >> 16);
}
__device__ __forceinline__ float bf2f(unsigned short h) {
  union { uint32_t u; float f; } v; v.u = ((uint32_t)h) << 16;
  return v.f;
}

// ---------------- wave helpers (wave64) ----------------
__device__ __forceinline__ float wsum(float v) {
#pragma unroll
  for (int m = 32; m >= 1; m >>= 1) v += __shfl_xor(v, m, 64);
  return v;
}
__device__ __forceinline__ float wmax(float v) {
#pragma unroll
  for (int m = 32; m >= 1; m >>= 1) v = fmaxf(v, __shfl_xor(v, m, 64));
  return v;
}

__device__ __forceinline__ float gelu_tanh(float x) {
  const float k0 = 0.7978845608028654f;  // sqrt(2/pi)
  float x3 = x * x * x;
  return 0.5f * x * (1.f + tanhf(k0 * (x + 0.044715f * x3)));
}

// ---------------- async global->LDS 16B ----------------
__device__ __forceinline__ void glds16(const unsigned short* g, unsigned short* l) {
  __builtin_amdgcn_global_load_lds((const __attribute__((address_space(1))) void*)g,
                                   (__attribute__((address_space(3))) void*)l, 16, 0, 0);
}

// ---------------- merged: weight transpose/convert + bias concat + LN1 ----------------
// bid ranges: [0,3072) = weight transpose tiles, 3072 = bias concat,
//             [3073, 3073+2048) = LN1 rows.
__global__ __launch_bounds__(256) void prep_kernel(
    const float* __restrict__ Wq, const float* __restrict__ Wk,
    const float* __restrict__ Wv, const float* __restrict__ Wo,
    const float* __restrict__ W1, const float* __restrict__ W2,
    unsigned short* __restrict__ Wcat_hi, unsigned short* __restrict__ Wcat_lo,
    unsigned short* __restrict__ Wo_t, unsigned short* __restrict__ W1_t,
    unsigned short* __restrict__ W2_t,
    const float* __restrict__ bq, const float* __restrict__ bk,
    const float* __restrict__ bv, float* __restrict__ bias_cat,
    const float* __restrict__ x, const float* __restrict__ ln1s,
    const float* __restrict__ ln1b,
    unsigned short* __restrict__ xn_hi, unsigned short* __restrict__ xn_lo) {
  __shared__ float t[32][33];
  __shared__ float red[2][4];
  int bid = blockIdx.x;
  int tid = threadIdx.x;
  if (bid == 3072) {  // bias concat
    for (int i = tid; i < 512; i += 256) {
      bias_cat[i] = bq[i];
      bias_cat[512 + i] = bk[i];
      bias_cat[1024 + i] = bv[i];
    }
    return;
  }
  if (bid > 3072) {  // LN1 row
    int row = bid - 3073;
    const float* xr = x + (size_t)row * DIMn;
    float2 xv = *(const float2*)(xr + tid * 2);
    float s  = xv.x + xv.y;
    float s2 = xv.x * xv.x + xv.y * xv.y;
    s = wsum(s); s2 = wsum(s2);
    int wv = tid >> 6;
    if ((tid & 63) == 0) { red[0][wv] = s; red[1][wv] = s2; }
    __syncthreads();
    s  = red[0][0] + red[0][1] + red[0][2] + red[0][3];
    s2 = red[1][0] + red[1][1] + red[1][2] + red[1][3];
    float mean = s * (1.f / DIMn);
    float var  = s2 * (1.f / DIMn) - mean * mean;
    float rstd = rsqrtf(var + 1e-6f);
    int d = tid * 2;
    float2 gv = *(const float2*)(ln1s + d);
    float2 bv2 = *(const float2*)(ln1b + d);
    float o0 = (xv.x - mean) * rstd * gv.x + bv2.x;
    float o1 = (xv.y - mean) * rstd * gv.y + bv2.y;
    size_t idx = (size_t)row * DIMn + d;
    unsigned short h0 = f2bf(o0), h1 = f2bf(o1);
    ushort2 hv; hv.x = h0; hv.y = h1;
    *(ushort2*)(xn_hi + idx) = hv;
    ushort2 lv; lv.x = f2bf(o0 - bf2f(h0)); lv.y = f2bf(o1 - bf2f(h1));
    *(ushort2*)(xn_lo + idx) = lv;
    return;
  }
  // weight transpose tile
  const float* W;
  unsigned short* hi;
  unsigned short* lo = nullptr;
  int K, N, tix;
  if (bid < 256)       { W = Wq; hi = Wcat_hi;               lo = Wcat_lo;               K = 512;  N = 512;  tix = bid; }
  else if (bid < 512)  { W = Wk; hi = Wcat_hi + 512 * 512;   lo = Wcat_lo + 512 * 512;   K = 512;  N = 512;  tix = bid - 256; }
  else if (bid < 768)  { W = Wv; hi = Wcat_hi + 1024 * 512;  K = 512;  N = 512;  tix = bid - 512; }
  else if (bid < 1024) { W = Wo; hi = Wo_t;                  K = 512;  N = 512;  tix = bid - 768; }
  else if (bid < 2048) { W = W1; hi = W1_t;                  K = 512;  N = 2048; tix = bid - 1024; }
  else                 { W = W2; hi = W2_t;                  K = 2048; N = 512;  tix = bid - 2048; }
  int ntn = N >> 5;
  int kt = tix / ntn, nt = tix - kt * ntn;
  int k0 = kt * 32, n0 = nt * 32;
  for (int i = tid; i < 1024; i += 256) {
    int r = i >> 5, c = i & 31;
    t[r][c] = W[(size_t)(k0 + r) * N + n0 + c];
  }
  __syncthreads();
  for (int i = tid; i < 1024; i += 256) {
    int r = i >> 5, c = i & 31;
    float v = t[c][r];
    unsigned short h = f2bf(v);
    size_t oi = (size_t)(n0 + r) * K + k0 + c;
    hi[oi] = h;
    if (lo) lo[oi] = f2bf(v - bf2f(h));
  }
}

// ---------------- LayerNorm -> bf16 (plain) ----------------
__global__ __launch_bounds__(256) void ln_kernel(const float* __restrict__ x,
                                                 const float* __restrict__ g,
                                                 const float* __restrict__ be,
                                                 unsigned short* __restrict__ yhi) {
  __shared__ float red[2][4];
  int row = blockIdx.x;
  int tid = threadIdx.x;
  const float* xr = x + (size_t)row * DIMn;
  float2 xv = *(const float2*)(xr + tid * 2);
  float s  = xv.x + xv.y;
  float s2 = xv.x * xv.x + xv.y * xv.y;
  s = wsum(s); s2 = wsum(s2);
  int wv = tid >> 6;
  if ((tid & 63) == 0) { red[0][wv] = s; red[1][wv] = s2; }
  __syncthreads();
  s  = red[0][0] + red[0][1] + red[0][2] + red[0][3];
  s2 = red[1][0] + red[1][1] + red[1][2] + red[1][3];
  float mean = s * (1.f / DIMn);
  float var  = s2 * (1.f / DIMn) - mean * mean;
  float rstd = rsqrtf(var + 1e-6f);
  int d = tid * 2;
  float2 gv = *(const float2*)(g + d);
  float2 bv = *(const float2*)(be + d);
  float o0 = (xv.x - mean) * rstd * gv.x + bv.x;
  float o1 = (xv.y - mean) * rstd * gv.y + bv.y;
  size_t idx = (size_t)row * DIMn + d;
  ushort2 hv; hv.x = f2bf(o0); hv.y = f2bf(o1);
  *(ushort2*)(yhi + idx) = hv;
}

// ---------------- bf16 MFMA GEMM: C = A @ Bt^T ----------------
// SPLIT: 0=plain, 1=full split-bf16, 2=hybrid (split only where bn<1024).
// EPI: 0=bias, 1=bias+res, 2=bias+gelu.
template <int BM, int BN, int BKT, int SPLIT, int EPI, int OUTBF16>
__global__ __launch_bounds__(256) void gemm_mfma(
    const unsigned short* __restrict__ Ahi, const unsigned short* __restrict__ Alo,
    const unsigned short* __restrict__ Bhi, const unsigned short* __restrict__ Blo,
    const float* __restrict__ bias, const float* __restrict__ res,
    void* __restrict__ outp, int M, int N, int K) {
  constexpr int FI = BM / 32, FJ = BN / 32;
  constexpr int AE = BM * BKT, BE = BN * BKT;
  constexpr int NB = (SPLIT > 0) ? 2 : 1;
  constexpr int CPR = BKT / 8;   // 16B chunks per row
  constexpr int ACH = BM * CPR, BCH = BN * CPR;
  __shared__ unsigned short smem[NB * (AE + BE)];
  unsigned short* AsHi = smem;
  unsigned short* AsLo = smem + ((SPLIT > 0) ? AE : 0);
  unsigned short* BsHi = smem + NB * AE;
  unsigned short* BsLo = BsHi + ((SPLIT > 0) ? BE : 0);

  int tid = threadIdx.x;
  int lane = tid & 63;
  int wid = tid >> 6;
  int wm = (wid >> 1) * (BM / 2), wn = (wid & 1) * (BN / 2);
  int bm = blockIdx.y * BM, bn = blockIdx.x * BN;
  int m16 = lane & 15, kg = lane >> 4;
  bool dos = (SPLIT == 1) || (SPLIT == 2 && bn < 1024);

  floatx4 acc[FI][FJ];
#pragma unroll
  for (int i = 0; i < FI; ++i)
#pragma unroll
    for (int j = 0; j < FJ; ++j) { floatx4 z = {0.f, 0.f, 0.f, 0.f}; acc[i][j] = z; }

  const unsigned short* aph = Ahi + (size_t)bm * K;
  const unsigned short* bph = Bhi + (size_t)bn * K;
  const unsigned short* apl = (SPLIT > 0) ? (Alo + (size_t)bm * K) : nullptr;
  const unsigned short* bpl = (SPLIT > 0) ? (Blo + (size_t)bn * K) : nullptr;

  for (int k0 = 0; k0 < K; k0 += BKT) {
#pragma unroll
    for (int c = tid; c < ACH; c += 256) {
      int row = c / CPR, kk = (c % CPR) * 8;
      glds16(aph + (size_t)row * K + k0 + kk, AsHi + c * 8);
      if (SPLIT > 0 && dos) glds16(apl + (size_t)row * K + k0 + kk, AsLo + c * 8);
    }
#pragma unroll
    for (int c = tid; c < BCH; c += 256) {
      int row = c / CPR, kk = (c % CPR) * 8;
      glds16(bph + (size_t)row * K + k0 + kk, BsHi + c * 8);
      if (SPLIT > 0 && dos) glds16(bpl + (size_t)row * K + k0 + kk, BsLo + c * 8);
    }
    __syncthreads();

#pragma unroll
    for (int ks = 0; ks < BKT / 32; ++ks) {
      short8 ah[FI], bh[FJ];
      short8 al[(SPLIT > 0) ? FI : 1], bl[(SPLIT > 0) ? FJ : 1];
#pragma unroll
      for (int i = 0; i < FI; ++i) {
        int r = wm + i * 16 + m16;
        ah[i] = *(const short8*)&AsHi[r * BKT + ks * 32 + kg * 8];
        if (SPLIT > 0 && dos) al[i] = *(const short8*)&AsLo[r * BKT + ks * 32 + kg * 8];
      }
#pragma unroll
      for (int j = 0; j < FJ; ++j) {
        int r = wn + j * 16 + m16;
        bh[j] = *(const short8*)&BsHi[r * BKT + ks * 32 + kg * 8];
        if (SPLIT > 0 && dos) bl[j] = *(const short8*)&BsLo[r * BKT + ks * 32 + kg * 8];
      }
#pragma unroll
      for (int i = 0; i < FI; ++i)
#pragma unroll
        for (int j = 0; j < FJ; ++j) {
          acc[i][j] = __builtin_amdgcn_mfma_f32_16x16x32_bf16(ah[i], bh[j], acc[i][j], 0, 0, 0);
          if (SPLIT > 0) {
            if (dos) {
              acc[i][j] = __builtin_amdgcn_mfma_f32_16x16x32_bf16(al[i], bh[j], acc[i][j], 0, 0, 0);
              acc[i][j] = __builtin_amdgcn_mfma_f32_16x16x32_bf16(ah[i], bl[j], acc[i][j], 0, 0, 0);
            }
          }
        }
    }
    __syncthreads();
  }

  // epilogue: C/D map col=lane&15, row=(lane>>4)*4+reg
#pragma unroll
  for (int i = 0; i < FI; ++i) {
    int gr0 = bm + wm + i * 16 + kg * 4;
#pragma unroll
    for (int j = 0; j < FJ; ++j) {
      int gc = bn + wn + j * 16 + m16;
      float bsv = bias[gc];
#pragma unroll
      for (int r = 0; r < 4; ++r) {
        size_t idx = (size_t)(gr0 + r) * N + gc;
        float v = acc[i][j][r] + bsv;
        if constexpr (EPI == 1) v += res[idx];
        if constexpr (EPI == 2) v = gelu_tanh(v);
        if constexpr (OUTBF16) ((unsigned short*)outp)[idx] = f2bf(v);
        else ((float*)outp)[idx] = v;
      }
    }
  }
}

// ---------------- fused hash+RoPE+expmap0 + windowed Poincare attention ----------------
__global__ __launch_bounds__(256) void attn_fused(const float* __restrict__ qkv,
                                                  const float* __restrict__ fcos,
                                                  const float* __restrict__ fsin,
                                                  const float* __restrict__ cvec,
                                                  const float* __restrict__ geo,
                                                  const float* __restrict__ hash,
                                                  unsigned short* __restrict__ attn_out) {
  __shared__ unsigned short Qhi[32][72], Qlo[32][72];   // pad 72: 2-way aliasing only
  __shared__ unsigned short Khi[96][72], Klo[96][72];
  __shared__ unsigned short Vt[64][104];                // V^T [d][key], bf16
  __shared__ unsigned short Pb[32][104];                // softmax weights [query][key]
  __shared__ float Sf[32][97];
  __shared__ float x2s[32], bxs[32], y2s[96], gys[96];

  int tid = threadIdx.x, lane = tid & 63, wv = tid >> 6;
  int bid = blockIdx.x;  // 512 = B*NH*(N/32)
  int nt = bid & 31, h = (bid >> 5) & 7, b = bid >> 8;
  int n0 = nt * 32;
  float c = cvec[b];
  float sqc = sqrtf(c);
  float rsqc = 1.f / sqc;
  float gs = geo[h];
  int dr = lane & 31;
  bool hih = lane >= 32;
  const float LOG9 = 2.1972245773362196f;
  float hofr = hash[h * HDn + dr] * LOG9;
  float hofi = hash[h * HDn + dr + 32] * LOG9;

  for (int i = tid; i < 32 * 52; i += 256) ((uint32_t*)Pb)[i] = 0u;

#pragma unroll
  for (int i = 0; i < 8; ++i) {
    int q = wv * 8 + i;
    int n = n0 + q;
    size_t bas = (size_t)(b * Nn + n) * QKVS + h * HDn;
    float qr = qkv[bas + dr] + hofr;
    float qi = qkv[bas + dr + 32] + hofi;
    float cs = fcos[n * 32 + dr], sn = fsin[n * 32 + dr];
    float qv = hih ? (qr * sn + qi * cs) : (qr * cs - qi * sn);
    float nq = sqrtf(wsum(qv * qv));
    float sq = fmaxf(nq, EPSF);
    float t = sqc * sq;
    float em = expf(-2.f * t);
    float opem = 1.f + em;
    float mag = ((1.f - em) / opem) * rsqc;
    float sech2 = 4.f * em / (opem * opem);
    float oq = (nq < EPSF) ? 0.f : mag * (qv / sq);
    unsigned short hh = f2bf(oq);
    Qhi[q][lane] = hh;
    Qlo[q][lane] = f2bf(oq - bf2f(hh));
    if (lane == 0) {
      x2s[q] = (nq < EPSF) ? 0.f : mag * mag;
      bxs[q] = (nq < EPSF) ? 1.f : sech2;
    }
  }
#pragma unroll 4
  for (int i = 0; i < 24; ++i) {
    int r = wv * 24 + i;
    int gi = n0 - 64 + r;
    float ok = 0.f, vf = 0.f, y2 = 0.f, gy = 1.f;
    if (gi >= 0) {
      size_t bas = (size_t)(b * Nn + gi) * QKVS + h * HDn;
      float kr = qkv[bas + 512 + dr];
      float ki = qkv[bas + 512 + dr + 32];
      vf = qkv[bas + 1024 + lane];
      float cs = fcos[gi * 32 + dr], sn = fsin[gi * 32 + dr];
      float kv = hih ? (kr * sn + ki * cs) : (kr * cs - ki * sn);
      float nk = sqrtf(wsum(kv * kv));
      float sk = fmaxf(nk, EPSF);
      float t = sqc * sk;
      float em = expf(-2.f * t);
      float opem = 1.f + em;
      float mag = ((1.f - em) / opem) * rsqc;
      float sech2 = 4.f * em / (opem * opem);
      ok = (nk < EPSF) ? 0.f : mag * (kv / sk);
      y2 = (nk < EPSF) ? 0.f : mag * mag;
      gy = (nk < EPSF) ? 1.f : sech2;
    }
    unsigned short hh = f2bf(ok);
    Khi[r][lane] = hh;
    Klo[r][lane] = f2bf(ok - bf2f(hh));
    Vt[lane][r] = f2bf(vf);
    if (lane == 0) { y2s[r] = y2; gys[r] = gy; }
  }
  __syncthreads();

  int m16 = lane & 15, kg = lane >> 4;
  int mt = wv >> 1;
#pragma unroll
  for (int j = 0; j < 3; ++j) {
    int ntile = (wv & 1) * 3 + j;
    floatx4 acc = {0.f, 0.f, 0.f, 0.f};
#pragma unroll
    for (int ks = 0; ks < 2; ++ks) {
      short8 ah = *(const short8*)&Qhi[mt * 16 + m16][ks * 32 + kg * 8];
      short8 al = *(const short8*)&Qlo[mt * 16 + m16][ks * 32 + kg * 8];
      short8 bh = *(const short8*)&Khi[ntile * 16 + m16][ks * 32 + kg * 8];
      short8 bl = *(const short8*)&Klo[ntile * 16 + m16][ks * 32 + kg * 8];
      acc = __builtin_amdgcn_mfma_f32_16x16x32_bf16(ah, bh, acc, 0, 0, 0);
      acc = __builtin_amdgcn_mfma_f32_16x16x32_bf16(al, bh, acc, 0, 0, 0);
      acc = __builtin_amdgcn_mfma_f32_16x16x32_bf16(ah, bl, acc, 0, 0, 0);
    }
#pragma unroll
    for (int r = 0; r < 4; ++r) Sf[mt * 16 + kg * 4 + r][ntile * 16 + m16] = acc[r];
  }
  __syncthreads();

  for (int i = 0; i < 8; ++i) {
    int nl = wv * 8 + i;
    int r = nl + 1 + lane;
    float xy = Sf[nl][r];
    float x2 = x2s[nl], y2 = y2s[r];
    float bx = bxs[nl], gy = gys[r];

    float den = fmaf(c * c * x2, y2, fmaf(-2.f * c, xy, 1.f));
    den = fmaxf(den, EPSF);
    float rden = 1.f / den;
    float s2 = fmaxf(x2 - 2.f * xy + y2, 0.f);
    float z = sqrtf(c * s2 * rden);
    float omz2 = bx * gy * rden;
    float opz = 1.f + fminf(z, 1.f);
    float ratio = fminf(opz * opz / omz2, 1.9999999e7f);
    float sc = -gs * logf(ratio) * rsqc;

    float mx = wmax(sc);
    float e = expf(sc - mx);
    float se = wsum(e);
    Pb[nl][r] = f2bf(e / se);
  }
  __syncthreads();

#pragma unroll
  for (int nt2 = 0; nt2 < 2; ++nt2) {
    int ntile = (wv & 1) * 2 + nt2;
    floatx4 acc = {0.f, 0.f, 0.f, 0.f};
#pragma unroll
    for (int ks = 0; ks < 3; ++ks) {
      short8 a = *(const short8*)&Pb[mt * 16 + m16][ks * 32 + kg * 8];
      short8 bb = *(const short8*)&Vt[ntile * 16 + m16][ks * 32 + kg * 8];
      acc = __builtin_amdgcn_mfma_f32_16x16x32_bf16(a, bb, acc, 0, 0, 0);
    }
#pragma unroll
    for (int r = 0; r < 4; ++r) {
      int qrow = mt * 16 + kg * 4 + r;
      int d = ntile * 16 + m16;
      attn_out[(size_t)(b * Nn + n0 + qrow) * DIMn + h * HDn + d] = f2bf(acc[r]);
    }
  }
}

// ---------------- launcher ----------------
extern "C" void kernel_launch(void* const* d_in, const int* in_sizes, int n_in,
                              void* d_out, int out_size, void* d_ws, size_t ws_size,
                              hipStream_t stream) {
  const float* x    = (const float*)d_in[0];
  const float* fcos = (const float*)d_in[1];
  const float* fsin = (const float*)d_in[2];
  const float* cvec = (const float*)d_in[3];
  const float* Wq = (const float*)d_in[4];  const float* bq = (const float*)d_in[5];
  const float* Wk = (const float*)d_in[6];  const float* bk = (const float*)d_in[7];
  const float* Wv = (const float*)d_in[8];  const float* bv = (const float*)d_in[9];
  const float* Wo = (const float*)d_in[10]; const float* bo = (const float*)d_in[11];
  const float* W1 = (const float*)d_in[12]; const float* b1 = (const float*)d_in[13];
  const float* W2 = (const float*)d_in[14]; const float* b2 = (const float*)d_in[15];
  const float* ln1s = (const float*)d_in[16]; const float* ln1b = (const float*)d_in[17];
  const float* ln2s = (const float*)d_in[18]; const float* ln2b = (const float*)d_in[19];
  const float* geo  = (const float*)d_in[20]; const float* hash = (const float*)d_in[21];
  float* out = (float*)d_out;
  char* base = (char*)d_ws;

  unsigned short* Wcat_hi = (unsigned short*)(base + 0);         // 1536x512 bf16
  unsigned short* Wcat_lo = (unsigned short*)(base + 1572864);
  unsigned short* Wo_t    = (unsigned short*)(base + 3145728);   // 512x512
  unsigned short* W1_t    = (unsigned short*)(base + 3670016);   // 2048x512
  unsigned short* W2_t    = (unsigned short*)(base + 5767168);   // 512x2048
  unsigned short* xn_hi   = (unsigned short*)(base + 7864320);   // 2048x512
  unsigned short* xn_lo   = (unsigned short*)(base + 9961472);
  float*          qkv     = (float*)(base + 12058624);           // 2048x1536 f32
  unsigned short* attnb   = (unsigned short*)(base + 7864320);   // reuse xn_hi
  float*          xout    = (float*)(base + 9961472);            // 2048x512 f32 (reuse)
  unsigned short* hbuf    = (unsigned short*)(base + 14155776);  // 2048x512
  unsigned short* mid     = (unsigned short*)(base + 16252928);  // 2048x2048
  float*          bias_cat= (float*)(base + 24641536);           // 1536 f32

  const int M = Bn * Nn;  // 2048

  // 1) weight conversion + bias concat + LN1 (merged)
  prep_kernel<<<3073 + M, 256, 0, stream>>>(Wq, Wk, Wv, Wo, W1, W2, Wcat_hi, Wcat_lo,
                                            Wo_t, W1_t, W2_t, bq, bk, bv, bias_cat,
                                            x, ln1s, ln1b, xn_hi, xn_lo);
  // 2) QKV GEMM, hybrid split, 64x64 BK=64 -> grid 24x32 = 768
  gemm_mfma<64, 64, 64, 2, 0, 0><<<dim3(QKVS / 64, M / 64), 256, 0, stream>>>(
      xn_hi, xn_lo, Wcat_hi, Wcat_lo, bias_cat, nullptr, qkv, M, QKVS, 512);
  // 3) fused rope + windowed Poincare attention -> attnb bf16 [M][512]
  attn_fused<<<Bn * NHn * (Nn / 32), 256, 0, stream>>>(qkv, fcos, fsin, cvec, geo, hash, attnb);
  // 4) Wo + residual(x) -> xout f32; 64x64 BK=128 -> grid 8x32 = 256
  gemm_mfma<64, 64, 128, 0, 1, 0><<<dim3(DIMn / 64, M / 64), 256, 0, stream>>>(
      attnb, nullptr, Wo_t, nullptr, bo, x, xout, M, DIMn, 512);
  // 5) LN2 -> hbuf bf16
  ln_kernel<<<M, 256, 0, stream>>>(xout, ln2s, ln2b, hbuf);
  // 6) FFN1 + gelu -> mid bf16; 128x128 BK=64 -> grid 16x16 = 256
  gemm_mfma<128, 128, 64, 0, 2, 1><<<dim3(2048 / 128, M / 128), 256, 0, stream>>>(
      hbuf, nullptr, W1_t, nullptr, b1, nullptr, mid, M, 2048, 512);
  // 7) FFN2 + residual(xout) -> out f32; 64x64 BK=128 -> grid 8x32 = 256
  gemm_mfma<64, 64, 128, 0, 1, 0><<<dim3(DIMn / 64, M / 64), 256, 0, stream>>>(
      mid, nullptr, W2_t, nullptr, b2, xout, out, M, DIMn, 2048);
}

// Round 7
// 193.762 us; speedup vs baseline: 1.1392x; 1.1392x over previous
//
#include <hip/hip_runtime.h>
#include <math.h>
#include <stdint.h>

#define Bn   2
#define Nn   1024
#define DIMn 512
#define NHn  8
#define HDn  64
#define QKVS 1536
#define EPSF 1e-7f

typedef __attribute__((ext_vector_type(8))) short short8;
typedef __attribute__((ext_vector_type(4))) float floatx4;

// ---------------- bf16 helpers (RNE) ----------------
__device__ __forceinline__ unsigned short f2bf(float f) {
  union { float f; uint32_t u; } v; v.f = f;
  uint32_t u = v.u;
  return (unsigned short)((u + 0x7FFFu + ((u >> 16) & 1u)) >> 16);
}
__device__ __forceinline__ float bf2f(unsigned short h) {
  union { uint32_t u; float f; } v; v.u = ((uint32_t)h) << 16;
  return v.f;
}

// ---------------- wave helpers (wave64) ----------------
__device__ __forceinline__ float wsum(float v) {
#pragma unroll
  for (int m = 32; m >= 1; m >>= 1) v += __shfl_xor(v, m, 64);
  return v;
}
__device__ __forceinline__ float wmax(float v) {
#pragma unroll
  for (int m = 32; m >= 1; m >>= 1) v = fmaxf(v, __shfl_xor(v, m, 64));
  return v;
}

__device__ __forceinline__ float gelu_tanh(float x) {
  const float k0 = 0.7978845608028654f;  // sqrt(2/pi)
  float x3 = x * x * x;
  return 0.5f * x * (1.f + tanhf(k0 * (x + 0.044715f * x3)));
}

// ---------------- async global->LDS 16B ----------------
__device__ __forceinline__ void glds16(const unsigned short* g, unsigned short* l) {
  __builtin_amdgcn_global_load_lds((const __attribute__((address_space(1))) void*)g,
                                   (__attribute__((address_space(3))) void*)l, 16, 0, 0);
}

// ---------------- merged: weight transpose/convert + bias concat + LN1 ----------------
__global__ __launch_bounds__(256) void prep_kernel(
    const float* __restrict__ Wq, const float* __restrict__ Wk,
    const float* __restrict__ Wv, const float* __restrict__ Wo,
    const float* __restrict__ W1, const float* __restrict__ W2,
    unsigned short* __restrict__ Wcat_hi, unsigned short* __restrict__ Wcat_lo,
    unsigned short* __restrict__ Wo_t, unsigned short* __restrict__ W1_t,
    unsigned short* __restrict__ W2_t,
    const float* __restrict__ bq, const float* __restrict__ bk,
    const float* __restrict__ bv, float* __restrict__ bias_cat,
    const float* __restrict__ x, const float* __restrict__ ln1s,
    const float* __restrict__ ln1b,
    unsigned short* __restrict__ xn_hi, unsigned short* __restrict__ xn_lo) {
  __shared__ float t[32][33];
  __shared__ float red[2][4];
  int bid = blockIdx.x;
  int tid = threadIdx.x;
  if (bid == 3072) {  // bias concat
    for (int i = tid; i < 512; i += 256) {
      bias_cat[i] = bq[i];
      bias_cat[512 + i] = bk[i];
      bias_cat[1024 + i] = bv[i];
    }
    return;
  }
  if (bid > 3072) {  // LN1 row
    int row = bid - 3073;
    const float* xr = x + (size_t)row * DIMn;
    float2 xv = *(const float2*)(xr + tid * 2);
    float s  = xv.x + xv.y;
    float s2 = xv.x * xv.x + xv.y * xv.y;
    s = wsum(s); s2 = wsum(s2);
    int wv = tid >> 6;
    if ((tid & 63) == 0) { red[0][wv] = s; red[1][wv] = s2; }
    __syncthreads();
    s  = red[0][0] + red[0][1] + red[0][2] + red[0][3];
    s2 = red[1][0] + red[1][1] + red[1][2] + red[1][3];
    float mean = s * (1.f / DIMn);
    float var  = s2 * (1.f / DIMn) - mean * mean;
    float rstd = rsqrtf(var + 1e-6f);
    int d = tid * 2;
    float2 gv = *(const float2*)(ln1s + d);
    float2 bv2 = *(const float2*)(ln1b + d);
    float o0 = (xv.x - mean) * rstd * gv.x + bv2.x;
    float o1 = (xv.y - mean) * rstd * gv.y + bv2.y;
    size_t idx = (size_t)row * DIMn + d;
    unsigned short h0 = f2bf(o0), h1 = f2bf(o1);
    ushort2 hv; hv.x = h0; hv.y = h1;
    *(ushort2*)(xn_hi + idx) = hv;
    ushort2 lv; lv.x = f2bf(o0 - bf2f(h0)); lv.y = f2bf(o1 - bf2f(h1));
    *(ushort2*)(xn_lo + idx) = lv;
    return;
  }
  // weight transpose tile
  const float* W;
  unsigned short* hi;
  unsigned short* lo = nullptr;
  int K, N, tix;
  if (bid < 256)       { W = Wq; hi = Wcat_hi;               lo = Wcat_lo;               K = 512;  N = 512;  tix = bid; }
  else if (bid < 512)  { W = Wk; hi = Wcat_hi + 512 * 512;   lo = Wcat_lo + 512 * 512;   K = 512;  N = 512;  tix = bid - 256; }
  else if (bid < 768)  { W = Wv; hi = Wcat_hi + 1024 * 512;  K = 512;  N = 512;  tix = bid - 512; }
  else if (bid < 1024) { W = Wo; hi = Wo_t;                  K = 512;  N = 512;  tix = bid - 768; }
  else if (bid < 2048) { W = W1; hi = W1_t;                  K = 512;  N = 2048; tix = bid - 1024; }
  else                 { W = W2; hi = W2_t;                  K = 2048; N = 512;  tix = bid - 2048; }
  int ntn = N >> 5;
  int kt = tix / ntn, nt = tix - kt * ntn;
  int k0 = kt * 32, n0 = nt * 32;
  for (int i = tid; i < 1024; i += 256) {
    int r = i >> 5, c = i & 31;
    t[r][c] = W[(size_t)(k0 + r) * N + n0 + c];
  }
  __syncthreads();
  for (int i = tid; i < 1024; i += 256) {
    int r = i >> 5, c = i & 31;
    float v = t[c][r];
    unsigned short h = f2bf(v);
    size_t oi = (size_t)(n0 + r) * K + k0 + c;
    hi[oi] = h;
    if (lo) lo[oi] = f2bf(v - bf2f(h));
  }
}

// ---------------- LayerNorm -> bf16 (plain) ----------------
__global__ __launch_bounds__(256) void ln_kernel(const float* __restrict__ x,
                                                 const float* __restrict__ g,
                                                 const float* __restrict__ be,
                                                 unsigned short* __restrict__ yhi) {
  __shared__ float red[2][4];
  int row = blockIdx.x;
  int tid = threadIdx.x;
  const float* xr = x + (size_t)row * DIMn;
  float2 xv = *(const float2*)(xr + tid * 2);
  float s  = xv.x + xv.y;
  float s2 = xv.x * xv.x + xv.y * xv.y;
  s = wsum(s); s2 = wsum(s2);
  int wv = tid >> 6;
  if ((tid & 63) == 0) { red[0][wv] = s; red[1][wv] = s2; }
  __syncthreads();
  s  = red[0][0] + red[0][1] + red[0][2] + red[0][3];
  s2 = red[1][0] + red[1][1] + red[1][2] + red[1][3];
  float mean = s * (1.f / DIMn);
  float var  = s2 * (1.f / DIMn) - mean * mean;
  float rstd = rsqrtf(var + 1e-6f);
  int d = tid * 2;
  float2 gv = *(const float2*)(g + d);
  float2 bv = *(const float2*)(be + d);
  float o0 = (xv.x - mean) * rstd * gv.x + bv.x;
  float o1 = (xv.y - mean) * rstd * gv.y + bv.y;
  size_t idx = (size_t)row * DIMn + d;
  ushort2 hv; hv.x = f2bf(o0); hv.y = f2bf(o1);
  *(ushort2*)(yhi + idx) = hv;
}

// ---------------- bf16 MFMA GEMM: C = A @ Bt^T ----------------
// SPLIT: 0=plain, 1=full split-bf16, 2=hybrid (split only where bn<1024).
// EPI: 0=bias, 1=bias+res, 2=bias+gelu.
template <int BM, int BN, int BKT, int SPLIT, int EPI, int OUTBF16>
__global__ __launch_bounds__(256) void gemm_mfma(
    const unsigned short* __restrict__ Ahi, const unsigned short* __restrict__ Alo,
    const unsigned short* __restrict__ Bhi, const unsigned short* __restrict__ Blo,
    const float* __restrict__ bias, const float* __restrict__ res,
    void* __restrict__ outp, int M, int N, int K) {
  constexpr int FI = BM / 32, FJ = BN / 32;
  constexpr int AE = BM * BKT, BE = BN * BKT;
  constexpr int NB = (SPLIT > 0) ? 2 : 1;
  constexpr int CPR = BKT / 8;   // 16B chunks per row
  constexpr int ACH = BM * CPR, BCH = BN * CPR;
  __shared__ unsigned short smem[NB * (AE + BE)];
  unsigned short* AsHi = smem;
  unsigned short* AsLo = smem + ((SPLIT > 0) ? AE : 0);
  unsigned short* BsHi = smem + NB * AE;
  unsigned short* BsLo = BsHi + ((SPLIT > 0) ? BE : 0);

  int tid = threadIdx.x;
  int lane = tid & 63;
  int wid = tid >> 6;
  int wm = (wid >> 1) * (BM / 2), wn = (wid & 1) * (BN / 2);
  int bm = blockIdx.y * BM, bn = blockIdx.x * BN;
  int m16 = lane & 15, kg = lane >> 4;
  bool dos = (SPLIT == 1) || (SPLIT == 2 && bn < 1024);

  floatx4 acc[FI][FJ];
#pragma unroll
  for (int i = 0; i < FI; ++i)
#pragma unroll
    for (int j = 0; j < FJ; ++j) { floatx4 z = {0.f, 0.f, 0.f, 0.f}; acc[i][j] = z; }

  const unsigned short* aph = Ahi + (size_t)bm * K;
  const unsigned short* bph = Bhi + (size_t)bn * K;
  const unsigned short* apl = (SPLIT > 0) ? (Alo + (size_t)bm * K) : nullptr;
  const unsigned short* bpl = (SPLIT > 0) ? (Blo + (size_t)bn * K) : nullptr;

  for (int k0 = 0; k0 < K; k0 += BKT) {
#pragma unroll
    for (int c = tid; c < ACH; c += 256) {
      int row = c / CPR, kk = (c % CPR) * 8;
      glds16(aph + (size_t)row * K + k0 + kk, AsHi + c * 8);
      if (SPLIT > 0 && dos) glds16(apl + (size_t)row * K + k0 + kk, AsLo + c * 8);
    }
#pragma unroll
    for (int c = tid; c < BCH; c += 256) {
      int row = c / CPR, kk = (c % CPR) * 8;
      glds16(bph + (size_t)row * K + k0 + kk, BsHi + c * 8);
      if (SPLIT > 0 && dos) glds16(bpl + (size_t)row * K + k0 + kk, BsLo + c * 8);
    }
    __syncthreads();

#pragma unroll
    for (int ks = 0; ks < BKT / 32; ++ks) {
      short8 ah[FI], bh[FJ];
      short8 al[(SPLIT > 0) ? FI : 1], bl[(SPLIT > 0) ? FJ : 1];
#pragma unroll
      for (int i = 0; i < FI; ++i) {
        int r = wm + i * 16 + m16;
        ah[i] = *(const short8*)&AsHi[r * BKT + ks * 32 + kg * 8];
        if (SPLIT > 0 && dos) al[i] = *(const short8*)&AsLo[r * BKT + ks * 32 + kg * 8];
      }
#pragma unroll
      for (int j = 0; j < FJ; ++j) {
        int r = wn + j * 16 + m16;
        bh[j] = *(const short8*)&BsHi[r * BKT + ks * 32 + kg * 8];
        if (SPLIT > 0 && dos) bl[j] = *(const short8*)&BsLo[r * BKT + ks * 32 + kg * 8];
      }
#pragma unroll
      for (int i = 0; i < FI; ++i)
#pragma unroll
        for (int j = 0; j < FJ; ++j) {
          acc[i][j] = __builtin_amdgcn_mfma_f32_16x16x32_bf16(ah[i], bh[j], acc[i][j], 0, 0, 0);
          if (SPLIT > 0) {
            if (dos) {
              acc[i][j] = __builtin_amdgcn_mfma_f32_16x16x32_bf16(al[i], bh[j], acc[i][j], 0, 0, 0);
              acc[i][j] = __builtin_amdgcn_mfma_f32_16x16x32_bf16(ah[i], bl[j], acc[i][j], 0, 0, 0);
            }
          }
        }
    }
    __syncthreads();
  }

  // epilogue: C/D map col=lane&15, row=(lane>>4)*4+reg
#pragma unroll
  for (int i = 0; i < FI; ++i) {
    int gr0 = bm + wm + i * 16 + kg * 4;
#pragma unroll
    for (int j = 0; j < FJ; ++j) {
      int gc = bn + wn + j * 16 + m16;
      float bsv = bias[gc];
#pragma unroll
      for (int r = 0; r < 4; ++r) {
        size_t idx = (size_t)(gr0 + r) * N + gc;
        float v = acc[i][j][r] + bsv;
        if constexpr (EPI == 1) v += res[idx];
        if constexpr (EPI == 2) v = gelu_tanh(v);
        if constexpr (OUTBF16) ((unsigned short*)outp)[idx] = f2bf(v);
        else ((float*)outp)[idx] = v;
      }
    }
  }
}

// ---------------- fused hash+RoPE+expmap0 + windowed Poincare attention ----------------
// 512 threads (8 waves) per block; block = (b, h, 32-query tile).
__global__ __launch_bounds__(512) void attn_fused(const float* __restrict__ qkv,
                                                  const float* __restrict__ fcos,
                                                  const float* __restrict__ fsin,
                                                  const float* __restrict__ cvec,
                                                  const float* __restrict__ geo,
                                                  const float* __restrict__ hash,
                                                  unsigned short* __restrict__ attn_out) {
  __shared__ unsigned short Qhi[32][72], Qlo[32][72];   // pad 72: 2-way aliasing only
  __shared__ unsigned short Khi[96][72], Klo[96][72];
  __shared__ unsigned short Vt[64][104];                // V^T [d][key], bf16
  __shared__ unsigned short Pb[32][104];                // softmax weights [query][key]
  __shared__ float Sf[32][97];
  __shared__ float x2s[32], bxs[32], y2s[96], gys[96];

  int tid = threadIdx.x, lane = tid & 63, wv = tid >> 6;  // wv in [0,8)
  int bid = blockIdx.x;  // 512 = B*NH*(N/32)
  int nt = bid & 31, h = (bid >> 5) & 7, b = bid >> 8;
  int n0 = nt * 32;
  float c = cvec[b];
  float sqc = sqrtf(c);
  float rsqc = 1.f / sqc;
  float gs = geo[h];
  int dr = lane & 31;
  bool hih = lane >= 32;
  const float LOG9 = 2.1972245773362196f;
  float hofr = hash[h * HDn + dr] * LOG9;
  float hofi = hash[h * HDn + dr + 32] * LOG9;

  for (int i = tid; i < 32 * 52; i += 512) ((uint32_t*)Pb)[i] = 0u;

  // --- stage Q (4 rows/wave) ---
#pragma unroll
  for (int i = 0; i < 4; ++i) {
    int q = wv * 4 + i;
    int n = n0 + q;
    size_t bas = (size_t)(b * Nn + n) * QKVS + h * HDn;
    float qr = qkv[bas + dr] + hofr;
    float qi = qkv[bas + dr + 32] + hofi;
    float cs = fcos[n * 32 + dr], sn = fsin[n * 32 + dr];
    float qv = hih ? (qr * sn + qi * cs) : (qr * cs - qi * sn);
    float nq = sqrtf(wsum(qv * qv));
    float sq = fmaxf(nq, EPSF);
    float t = sqc * sq;
    float em = expf(-2.f * t);
    float opem = 1.f + em;
    float mag = ((1.f - em) / opem) * rsqc;
    float sech2 = 4.f * em / (opem * opem);
    float oq = (nq < EPSF) ? 0.f : mag * (qv / sq);
    unsigned short hh = f2bf(oq);
    Qhi[q][lane] = hh;
    Qlo[q][lane] = f2bf(oq - bf2f(hh));
    if (lane == 0) {
      x2s[q] = (nq < EPSF) ? 0.f : mag * mag;
      bxs[q] = (nq < EPSF) ? 1.f : sech2;
    }
  }
  // --- stage K (12 rows/wave) + V^T ---
#pragma unroll 4
  for (int i = 0; i < 12; ++i) {
    int r = wv * 12 + i;
    int gi = n0 - 64 + r;
    float ok = 0.f, vf = 0.f, y2 = 0.f, gy = 1.f;
    if (gi >= 0) {
      size_t bas = (size_t)(b * Nn + gi) * QKVS + h * HDn;
      float kr = qkv[bas + 512 + dr];
      float ki = qkv[bas + 512 + dr + 32];
      vf = qkv[bas + 1024 + lane];
      float cs = fcos[gi * 32 + dr], sn = fsin[gi * 32 + dr];
      float kv = hih ? (kr * sn + ki * cs) : (kr * cs - ki * sn);
      float nk = sqrtf(wsum(kv * kv));
      float sk = fmaxf(nk, EPSF);
      float t = sqc * sk;
      float em = expf(-2.f * t);
      float opem = 1.f + em;
      float mag = ((1.f - em) / opem) * rsqc;
      float sech2 = 4.f * em / (opem * opem);
      ok = (nk < EPSF) ? 0.f : mag * (kv / sk);
      y2 = (nk < EPSF) ? 0.f : mag * mag;
      gy = (nk < EPSF) ? 1.f : sech2;
    }
    unsigned short hh = f2bf(ok);
    Khi[r][lane] = hh;
    Klo[r][lane] = f2bf(ok - bf2f(hh));
    Vt[lane][r] = f2bf(vf);
    if (lane == 0) { y2s[r] = y2; gys[r] = gy; }
  }
  __syncthreads();

  // --- S = Q K^T via split-bf16 MFMA: 12 tile-units (2 mt x 6 nt) over 8 waves ---
  int m16 = lane & 15, kg = lane >> 4;
#pragma unroll
  for (int uu = 0; uu < 2; ++uu) {
    int u = wv + uu * 8;
    if (u < 12) {
      int mt = u / 6, ntile = u % 6;
      floatx4 acc = {0.f, 0.f, 0.f, 0.f};
#pragma unroll
      for (int ks = 0; ks < 2; ++ks) {
        short8 ah = *(const short8*)&Qhi[mt * 16 + m16][ks * 32 + kg * 8];
        short8 al = *(const short8*)&Qlo[mt * 16 + m16][ks * 32 + kg * 8];
        short8 bh = *(const short8*)&Khi[ntile * 16 + m16][ks * 32 + kg * 8];
        short8 bl = *(const short8*)&Klo[ntile * 16 + m16][ks * 32 + kg * 8];
        acc = __builtin_amdgcn_mfma_f32_16x16x32_bf16(ah, bh, acc, 0, 0, 0);
        acc = __builtin_amdgcn_mfma_f32_16x16x32_bf16(al, bh, acc, 0, 0, 0);
        acc = __builtin_amdgcn_mfma_f32_16x16x32_bf16(ah, bl, acc, 0, 0, 0);
      }
#pragma unroll
      for (int r = 0; r < 4; ++r) Sf[mt * 16 + kg * 4 + r][ntile * 16 + m16] = acc[r];
    }
  }
  __syncthreads();

  // --- stable fp32 scores + softmax -> Pb bf16 (4 rows/wave) ---
#pragma unroll
  for (int i = 0; i < 4; ++i) {
    int nl = wv * 4 + i;
    int r = nl + 1 + lane;
    float xy = Sf[nl][r];
    float x2 = x2s[nl], y2 = y2s[r];
    float bx = bxs[nl], gy = gys[r];

    float den = fmaf(c * c * x2, y2, fmaf(-2.f * c, xy, 1.f));
    den = fmaxf(den, EPSF);
    float rden = 1.f / den;
    float s2 = fmaxf(x2 - 2.f * xy + y2, 0.f);
    float z = sqrtf(c * s2 * rden);
    float omz2 = bx * gy * rden;
    float opz = 1.f + fminf(z, 1.f);
    float ratio = fminf(opz * opz / omz2, 1.9999999e7f);
    float sc = -gs * logf(ratio) * rsqc;

    float mx = wmax(sc);
    float e = expf(sc - mx);
    float se = wsum(e);
    Pb[nl][r] = f2bf(e / se);
  }
  __syncthreads();

  // --- PV via MFMA: 8 tile-units (2 mt x 4 nt), one per wave ---
  {
    int mt = wv >> 2, ntile = wv & 3;
    floatx4 acc = {0.f, 0.f, 0.f, 0.f};
#pragma unroll
    for (int ks = 0; ks < 3; ++ks) {
      short8 a = *(const short8*)&Pb[mt * 16 + m16][ks * 32 + kg * 8];
      short8 bb = *(const short8*)&Vt[ntile * 16 + m16][ks * 32 + kg * 8];
      acc = __builtin_amdgcn_mfma_f32_16x16x32_bf16(a, bb, acc, 0, 0, 0);
    }
#pragma unroll
    for (int r = 0; r < 4; ++r) {
      int qrow = mt * 16 + kg * 4 + r;
      int d = ntile * 16 + m16;
      attn_out[(size_t)(b * Nn + n0 + qrow) * DIMn + h * HDn + d] = f2bf(acc[r]);
    }
  }
}

// ---------------- launcher ----------------
extern "C" void kernel_launch(void* const* d_in, const int* in_sizes, int n_in,
                              void* d_out, int out_size, void* d_ws, size_t ws_size,
                              hipStream_t stream) {
  const float* x    = (const float*)d_in[0];
  const float* fcos = (const float*)d_in[1];
  const float* fsin = (const float*)d_in[2];
  const float* cvec = (const float*)d_in[3];
  const float* Wq = (const float*)d_in[4];  const float* bq = (const float*)d_in[5];
  const float* Wk = (const float*)d_in[6];  const float* bk = (const float*)d_in[7];
  const float* Wv = (const float*)d_in[8];  const float* bv = (const float*)d_in[9];
  const float* Wo = (const float*)d_in[10]; const float* bo = (const float*)d_in[11];
  const float* W1 = (const float*)d_in[12]; const float* b1 = (const float*)d_in[13];
  const float* W2 = (const float*)d_in[14]; const float* b2 = (const float*)d_in[15];
  const float* ln1s = (const float*)d_in[16]; const float* ln1b = (const float*)d_in[17];
  const float* ln2s = (const float*)d_in[18]; const float* ln2b = (const float*)d_in[19];
  const float* geo  = (const float*)d_in[20]; const float* hash = (const float*)d_in[21];
  float* out = (float*)d_out;
  char* base = (char*)d_ws;

  unsigned short* Wcat_hi = (unsigned short*)(base + 0);         // 1536x512 bf16
  unsigned short* Wcat_lo = (unsigned short*)(base + 1572864);
  unsigned short* Wo_t    = (unsigned short*)(base + 3145728);   // 512x512
  unsigned short* W1_t    = (unsigned short*)(base + 3670016);   // 2048x512
  unsigned short* W2_t    = (unsigned short*)(base + 5767168);   // 512x2048
  unsigned short* xn_hi   = (unsigned short*)(base + 7864320);   // 2048x512
  unsigned short* xn_lo   = (unsigned short*)(base + 9961472);
  float*          qkv     = (float*)(base + 12058624);           // 2048x1536 f32
  unsigned short* attnb   = (unsigned short*)(base + 7864320);   // reuse xn_hi
  float*          xout    = (float*)(base + 9961472);            // 2048x512 f32 (reuse)
  unsigned short* hbuf    = (unsigned short*)(base + 14155776);  // 2048x512
  unsigned short* mid     = (unsigned short*)(base + 16252928);  // 2048x2048
  float*          bias_cat= (float*)(base + 24641536);           // 1536 f32

  const int M = Bn * Nn;  // 2048

  // 1) weight conversion + bias concat + LN1 (merged)
  prep_kernel<<<3073 + M, 256, 0, stream>>>(Wq, Wk, Wv, Wo, W1, W2, Wcat_hi, Wcat_lo,
                                            Wo_t, W1_t, W2_t, bq, bk, bv, bias_cat,
                                            x, ln1s, ln1b, xn_hi, xn_lo);
  // 2) QKV GEMM, hybrid split, 64x64 BK=32 -> grid 24x32 = 768 (R5 config)
  gemm_mfma<64, 64, 32, 2, 0, 0><<<dim3(QKVS / 64, M / 64), 256, 0, stream>>>(
      xn_hi, xn_lo, Wcat_hi, Wcat_lo, bias_cat, nullptr, qkv, M, QKVS, 512);
  // 3) fused rope + windowed Poincare attention (512-thread blocks) -> attnb bf16
  attn_fused<<<Bn * NHn * (Nn / 32), 512, 0, stream>>>(qkv, fcos, fsin, cvec, geo, hash, attnb);
  // 4) Wo + residual(x) -> xout f32; 32x64 BK=64 -> grid 8x64 = 512 (R5 config)
  gemm_mfma<32, 64, 64, 0, 1, 0><<<dim3(DIMn / 64, M / 32), 256, 0, stream>>>(
      attnb, nullptr, Wo_t, nullptr, bo, x, xout, M, DIMn, 512);
  // 5) LN2 -> hbuf bf16
  ln_kernel<<<M, 256, 0, stream>>>(xout, ln2s, ln2b, hbuf);
  // 6) FFN1 + gelu -> mid bf16; 64x128 BK=64 -> grid 16x32 = 512 (R5 config)
  gemm_mfma<64, 128, 64, 0, 2, 1><<<dim3(2048 / 128, M / 64), 256, 0, stream>>>(
      hbuf, nullptr, W1_t, nullptr, b1, nullptr, mid, M, 2048, 512);
  // 7) FFN2 + residual(xout) -> out f32; 32x64 BK=64 -> grid 8x64 = 512 (R5 config)
  gemm_mfma<32, 64, 64, 0, 1, 0><<<dim3(DIMn / 64, M / 32), 256, 0, stream>>>(
      mid, nullptr, W2_t, nullptr, b2, xout, out, M, DIMn, 2048);
}